// Round 10
// baseline (54.399 us; speedup 1.0000x reference)
//
#include <hip/hip_runtime.h>

#define S      4096
#define CIN    7
#define DM     512
#define KERN   73
#define TT     256
#define TILES  (S / TT)        // 16
#define NSTAGE (TT + 17)       // 273 valid staged elements per channel row
#define TROW   292             // row stride (16B aligned; covers float4 overreads)
#define CHUNK  32
#define NCH    (TT / CHUNK)    // 8

// 18-tap FIR on 32 consecutive t for a d-pair; dual-row windows, float2 stores.
__device__ __forceinline__ void do_chunk32_pair(const float* __restrict__ x0,
                                                const float* __restrict__ x1,
                                                const float g0[18], const float g1[18],
                                                float bias0, float bias1,
                                                float* __restrict__ opc)
{
    float a0[CHUNK], a1[CHUNK];
    #pragma unroll
    for (int i = 0; i < CHUNK; ++i) { a0[i] = bias0; a1[i] = bias1; }

    #pragma unroll
    for (int q = 0; q < 13; ++q) {
        float4 v0 = *reinterpret_cast<const float4*>(x0 + 4 * q);
        float4 v1 = *reinterpret_cast<const float4*>(x1 + 4 * q);
        float va0[4] = {v0.x, v0.y, v0.z, v0.w};
        float va1[4] = {v1.x, v1.y, v1.z, v1.w};
        #pragma unroll
        for (int e = 0; e < 4; ++e) {
            const int j = 4 * q + e;
            #pragma unroll
            for (int i = 0; i < CHUNK; ++i) {
                const int off = j - i;
                if (off >= 0 && off < 18) {
                    a0[i] = fmaf(g0[off], va0[e], a0[i]);
                    a1[i] = fmaf(g1[off], va1[e], a1[i]);
                }
            }
        }
        // pair (a0[i],a1[i]) final once last tap j=i+17 landed: i <= 4q-14
        if (q >= 4 && q < 12) {
            const int lo = (q == 4) ? 0 : (4 * q - 17);
            const int hi = 4 * q - 14;
            #pragma unroll
            for (int i = 0; i < CHUNK; ++i)
                if (i >= lo && i <= hi) {
                    float2 w = make_float2(a0[i], a1[i]);
                    *reinterpret_cast<float2*>(opc + i * DM) = w;
                }
        }
        if (q == 12) {
            float2 w = make_float2(a0[31], a1[31]);
            *reinterpret_cast<float2*>(opc + 31 * DM) = w;
        }
    }
}

__global__ __launch_bounds__(512, 2)
void tokemb_kernel(const float* __restrict__ x,
                   const float* __restrict__ w_conv,
                   const float* __restrict__ b_conv,
                   const float* __restrict__ w_left,
                   const float* __restrict__ b_left,
                   float* __restrict__ out)
{
    __shared__ float xs[CIN * TROW];

    const int blk  = blockIdx.x;
    const int b    = blk / TILES;
    const int tile = blk & (TILES - 1);
    const int t0   = tile * TT;
    const int tid  = threadIdx.x;

    // ---- stage x tile into LDS transposed: xs[c][j] = x[b, (t0-16+j) mod S, c]
    {
        const float* xb = x + (long long)b * S * CIN;
        const long long base = (long long)(t0 - 16) * CIN;
        const int nfl = CIN * NSTAGE;                        // 1911 floats
        for (int e4 = 4 * tid; e4 < nfl; e4 += 4 * 512) {
            long long src = base + e4;
            if (src >= 0 && src + 3 < (long long)S * CIN) {
                float4 v = *reinterpret_cast<const float4*>(xb + src);
                float va[4] = {v.x, v.y, v.z, v.w};
                #pragma unroll
                for (int u = 0; u < 4; ++u) {
                    int e = e4 + u;
                    int j = e / CIN, c = e - j * CIN;
                    xs[c * TROW + j] = va[u];
                }
            } else {
                #pragma unroll
                for (int u = 0; u < 4; ++u) {
                    int e = e4 + u;
                    if (e < nfl) {
                        int j = e / CIN, c = e - j * CIN;
                        int tm = t0 - 16 + j;
                        if (tm < 0) tm += S; else if (tm >= S) tm -= S;
                        xs[c * TROW + j] = xb[tm * CIN + c];
                    }
                }
            }
        }
    }

    // ---- thread owns d-pair (d0, d0+1); tg picks chunk half ----
    const int pid = tid & 255;
    const int tg  = tid >> 8;            // 0 -> chunks 0..3, 1 -> chunks 4..7
    const int d0  = 2 * pid;

    float g[2][18], bias[2];
    const float* xr[2];
    #pragma unroll
    for (int dd = 0; dd < 2; ++dd) {
        const int d  = d0 + dd;
        const int oo = d % KERN;
        const float* wrow = (d < DM - 1) ? (w_conv + oo * 18) : w_left;
        bias[dd] = (d < DM - 1) ? b_conv[oo] : b_left[0];
        const int cc = (d < DM - 1) ? (d / KERN) : (CIN - 1);
        xr[dd] = xs + cc * TROW;
        // FIR tap order: off = 15-3m+k -> g[off] = wrow[(5-off/3)*3 + off%3]
        #pragma unroll
        for (int off = 0; off < 18; ++off)
            g[dd][off] = wrow[(5 - off / 3) * 3 + (off % 3)];
    }

    __syncthreads();

    float* const op = out + ((long long)b * S + t0) * DM + d0;

    const int wid = tid >> 6;            // 0..7, de-phase within each tg
    const bool edgetile = (tile == 0) || (tile == TILES - 1);

    for (int cc_ = 0; cc_ < 4; ++cc_) {
        const int ch  = tg * 4 + ((cc_ + wid) & 3);
        const int jb  = ch * CHUNK;
        const int tc  = t0 + jb;
        float* opc = op + jb * DM;

        if (!edgetile || !((tc < 16) || (tc + CHUNK >= S))) {
            do_chunk32_pair(xr[0] + jb, xr[1] + jb, g[0], g[1],
                            bias[0], bias[1], opc);
        } else {
            // masked scalar path (tile 0 chunk 0, tile 15 chunk 7)
            #pragma unroll
            for (int dd = 0; dd < 2; ++dd) {
                const float* xw = xr[dd] + jb;
                #pragma unroll
                for (int i = 0; i < CHUNK; ++i) {
                    float p0 = 0.f, p1 = 0.f, p2 = 0.f;
                    #pragma unroll
                    for (int o = 0; o < 18; o += 3) {
                        p0 = fmaf(g[dd][o],     xw[i + o],     p0);
                        p1 = fmaf(g[dd][o + 1], xw[i + o + 1], p1);
                        p2 = fmaf(g[dd][o + 2], xw[i + o + 2], p2);
                    }
                    const int t = tc + i;
                    const float f0 = (t == 0 || t >= 16)     ? 1.f : 0.f;
                    const float f1 = (t >= 15)               ? 1.f : 0.f;
                    const float f2 = (t >= 14 && t != S - 1) ? 1.f : 0.f;
                    opc[i * DM + dd] = bias[dd] + f0 * p0 + f1 * p1 + f2 * p2;
                }
            }
        }
    }
}

extern "C" void kernel_launch(void* const* d_in, const int* in_sizes, int n_in,
                              void* d_out, int out_size, void* d_ws, size_t ws_size,
                              hipStream_t stream) {
    const float* x      = (const float*)d_in[0];
    const float* w_conv = (const float*)d_in[1];
    const float* b_conv = (const float*)d_in[2];
    const float* w_left = (const float*)d_in[3];
    const float* b_left = (const float*)d_in[4];
    float* out = (float*)d_out;

    const int B = in_sizes[0] / (S * CIN);   // 32
    dim3 grid(B * TILES);
    tokemb_kernel<<<grid, 512, 0, stream>>>(x, w_conv, b_conv, w_left, b_left, out);
}

// Round 11
// 48.721 us; speedup vs baseline: 1.1165x; 1.1165x over previous
//
#include <hip/hip_runtime.h>

#define S      4096
#define CIN    7
#define DM     512
#define KERN   73
#define TT     256
#define TILES  (S / TT)        // 16
#define NSTAGE (TT + 17)       // 273 valid staged elements per channel row
#define TROW   292             // row stride (16B aligned; covers float4 overreads)
#define CHUNK  32
#define NCH    (TT / CHUNK)    // 8

// Interior chunk: 18-tap FIR on 32 consecutive t. 13x ds_read_b128, store-ASAP.
__device__ __forceinline__ void do_chunk32(const float* __restrict__ xc,
                                           const float g[18], float bias,
                                           float* __restrict__ opc)
{
    float acc[CHUNK];
    #pragma unroll
    for (int i = 0; i < CHUNK; ++i) acc[i] = bias;

    #pragma unroll
    for (int q = 0; q < 13; ++q) {
        float4 v = *reinterpret_cast<const float4*>(xc + 4 * q);
        float va[4] = {v.x, v.y, v.z, v.w};
        #pragma unroll
        for (int e = 0; e < 4; ++e) {
            const int j = 4 * q + e;
            #pragma unroll
            for (int i = 0; i < CHUNK; ++i) {
                const int off = j - i;
                if (off >= 0 && off < 18)
                    acc[i] = fmaf(g[off], va[e], acc[i]);
            }
        }
        // store outputs whose last tap (j = i + 17) has landed: i <= 4q-14
        if (q >= 4 && q < 12) {
            const int lo = (q == 4) ? 0 : (4 * q - 17);
            const int hi = 4 * q - 14;
            #pragma unroll
            for (int i = 0; i < CHUNK; ++i)
                if (i >= lo && i <= hi) opc[i * DM] = acc[i];
        }
        if (q == 12) {
            opc[31 * DM] = acc[31];
        }
    }
}

__global__ __launch_bounds__(512, 2)
void tokemb_kernel(const float* __restrict__ x,
                   const float* __restrict__ w_conv,
                   const float* __restrict__ b_conv,
                   const float* __restrict__ w_left,
                   const float* __restrict__ b_left,
                   float* __restrict__ out)
{
    __shared__ float xs[CIN * TROW];

    const int blk  = blockIdx.x;
    const int b    = blk / TILES;
    const int tile = blk & (TILES - 1);
    const int t0   = tile * TT;
    const int tid  = threadIdx.x;

    // ---- stage x tile into LDS transposed: xs[c][j] = x[b, (t0-16+j) mod S, c]
    {
        const float* xb = x + (long long)b * S * CIN;
        const long long base = (long long)(t0 - 16) * CIN;
        const int nfl = CIN * NSTAGE;                        // 1911 floats
        for (int e4 = 4 * tid; e4 < nfl; e4 += 4 * 512) {
            long long src = base + e4;
            if (src >= 0 && src + 3 < (long long)S * CIN) {
                float4 v = *reinterpret_cast<const float4*>(xb + src);
                float va[4] = {v.x, v.y, v.z, v.w};
                #pragma unroll
                for (int u = 0; u < 4; ++u) {
                    int e = e4 + u;
                    int j = e / CIN, c = e - j * CIN;
                    xs[c * TROW + j] = va[u];
                }
            } else {
                #pragma unroll
                for (int u = 0; u < 4; ++u) {
                    int e = e4 + u;
                    if (e < nfl) {
                        int j = e / CIN, c = e - j * CIN;
                        int tm = t0 - 16 + j;
                        if (tm < 0) tm += S; else if (tm >= S) tm -= S;
                        xs[c * TROW + j] = xb[tm * CIN + c];
                    }
                }
            }
        }
    }

    // ---- per-thread weights in FIR tap order ----
    const int d  = tid;
    const int oo = d % KERN;
    const float* wrow = (d < DM - 1) ? (w_conv + oo * 18) : w_left;
    const float bias  = (d < DM - 1) ? b_conv[oo] : b_left[0];
    const int cc = (d < DM - 1) ? (d / KERN) : (CIN - 1);
    float g[18];
    #pragma unroll
    for (int off = 0; off < 18; ++off)
        g[off] = wrow[(5 - off / 3) * 3 + (off % 3)];

    __syncthreads();

    const float* xrow = xs + cc * TROW;
    float* const op = out + ((long long)b * S + t0) * DM + d;

    // A/B vs R8: NO wave de-phasing — all waves walk chunks in the same order
    // so the block's stores stay within one contiguous 64 KB t-window at a time
    // (L2 write-combining / HBM page locality test).
    const bool edgetile = (tile == 0) || (tile == TILES - 1);

    for (int cc_ = 0; cc_ < NCH; ++cc_) {
        const int ch  = cc_;
        const int jb  = ch * CHUNK;
        const int tc  = t0 + jb;
        float* opc = op + jb * DM;

        if (!edgetile || !((tc < 16) || (tc + CHUNK >= S))) {
            do_chunk32(xrow + jb, g, bias, opc);
        } else {
            // masked scalar path (only tile 0 chunk 0 and tile 15 chunk 7)
            #pragma unroll
            for (int i = 0; i < CHUNK; ++i) {
                float p0 = 0.f, p1 = 0.f, p2 = 0.f;
                #pragma unroll
                for (int o = 0; o < 18; o += 3) {
                    p0 = fmaf(g[o],     xrow[jb + i + o],     p0);
                    p1 = fmaf(g[o + 1], xrow[jb + i + o + 1], p1);
                    p2 = fmaf(g[o + 2], xrow[jb + i + o + 2], p2);
                }
                const int t = tc + i;
                const float f0 = (t == 0 || t >= 16)     ? 1.f : 0.f;
                const float f1 = (t >= 15)               ? 1.f : 0.f;
                const float f2 = (t >= 14 && t != S - 1) ? 1.f : 0.f;
                opc[i * DM] = bias + f0 * p0 + f1 * p1 + f2 * p2;
            }
        }
    }
}

extern "C" void kernel_launch(void* const* d_in, const int* in_sizes, int n_in,
                              void* d_out, int out_size, void* d_ws, size_t ws_size,
                              hipStream_t stream) {
    const float* x      = (const float*)d_in[0];
    const float* w_conv = (const float*)d_in[1];
    const float* b_conv = (const float*)d_in[2];
    const float* w_left = (const float*)d_in[3];
    const float* b_left = (const float*)d_in[4];
    float* out = (float*)d_out;

    const int B = in_sizes[0] / (S * CIN);   // 32
    dim3 grid(B * TILES);
    tokemb_kernel<<<grid, 512, 0, stream>>>(x, w_conv, b_conv, w_left, b_left, out);
}

// Round 13
// 48.078 us; speedup vs baseline: 1.1315x; 1.0134x over previous
//
#include <hip/hip_runtime.h>

#define S      4096
#define CIN    7
#define DM     512
#define KERN   73
#define TT     256
#define TILES  (S / TT)        // 16
#define NSTAGE (TT + 17)       // 273 valid staged elements per channel row
#define TROW   292             // row stride (16B aligned; covers float4 overreads)
#define CHUNK  32
#define NCH    (TT / CHUNK)    // 8

#if __has_builtin(__builtin_amdgcn_fdot2) && __has_builtin(__builtin_amdgcn_cvt_pkrtz)
#define USE_DOT2 1
#else
#define USE_DOT2 0
#endif

typedef _Float16 half2_t __attribute__((ext_vector_type(2)));
typedef __fp16   half2_raw __attribute__((ext_vector_type(2)));

#if USE_DOT2
static __device__ __forceinline__ half2_t pkrtz(float a, float b) {
    half2_raw r = __builtin_amdgcn_cvt_pkrtz(a, b);
    return __builtin_bit_cast(half2_t, r);
}

// 18-tap FIR on 32 t via v_dot2_f32_f16: windows f16-packed once per chunk
// (aligned + odd-phase pair arrays), 9 dot2 per output, fp32 accumulate.
__device__ __forceinline__ void do_chunk32_dot2(const float* __restrict__ xc,
                                                const half2_t g2[9], float bias,
                                                float* __restrict__ opc)
{
    float w[52];
    #pragma unroll
    for (int q = 0; q < 13; ++q) {
        float4 v = *reinterpret_cast<const float4*>(xc + 4 * q);
        w[4*q+0] = v.x; w[4*q+1] = v.y; w[4*q+2] = v.z; w[4*q+3] = v.w;
    }
    half2_t A[26], B[25];
    #pragma unroll
    for (int p = 0; p < 26; ++p) A[p] = pkrtz(w[2*p], w[2*p+1]);
    #pragma unroll
    for (int p = 0; p < 25; ++p) B[p] = pkrtz(w[2*p+1], w[2*p+2]);

    #pragma unroll
    for (int i = 0; i < CHUNK; ++i) {
        float a = bias;
        const int p0 = i >> 1;
        if ((i & 1) == 0) {
            #pragma unroll
            for (int m = 0; m < 9; ++m)
                a = __builtin_amdgcn_fdot2(g2[m], A[p0 + m], a, false);
        } else {
            #pragma unroll
            for (int m = 0; m < 9; ++m)
                a = __builtin_amdgcn_fdot2(g2[m], B[p0 + m], a, false);
        }
        opc[i * DM] = a;   // store as soon as this output finishes
    }
}
#endif

// fp32 scalar fallback path (R8 structure)
__device__ __forceinline__ void do_chunk32_fma(const float* __restrict__ xc,
                                               const float g[18], float bias,
                                               float* __restrict__ opc)
{
    float acc[CHUNK];
    #pragma unroll
    for (int i = 0; i < CHUNK; ++i) acc[i] = bias;
    #pragma unroll
    for (int q = 0; q < 13; ++q) {
        float4 v = *reinterpret_cast<const float4*>(xc + 4 * q);
        float va[4] = {v.x, v.y, v.z, v.w};
        #pragma unroll
        for (int e = 0; e < 4; ++e) {
            const int j = 4 * q + e;
            #pragma unroll
            for (int i = 0; i < CHUNK; ++i) {
                const int off = j - i;
                if (off >= 0 && off < 18)
                    acc[i] = fmaf(g[off], va[e], acc[i]);
            }
        }
        if (q >= 4 && q < 12) {
            const int lo = (q == 4) ? 0 : (4 * q - 17);
            const int hi = 4 * q - 14;
            #pragma unroll
            for (int i = 0; i < CHUNK; ++i)
                if (i >= lo && i <= hi) opc[i * DM] = acc[i];
        }
        if (q == 12) opc[31 * DM] = acc[31];
    }
}

__global__ __launch_bounds__(512, 2)
void tokemb_kernel(const float* __restrict__ x,
                   const float* __restrict__ w_conv,
                   const float* __restrict__ b_conv,
                   const float* __restrict__ w_left,
                   const float* __restrict__ b_left,
                   float* __restrict__ out)
{
    __shared__ float xs[CIN * TROW];

    const int blk  = blockIdx.x;
    const int b    = blk / TILES;
    const int tile = blk & (TILES - 1);
    const int t0   = tile * TT;
    const int tid  = threadIdx.x;

    // ---- stage x tile into LDS transposed: xs[c][j] = x[b, (t0-16+j) mod S, c]
    {
        const float* xb = x + (long long)b * S * CIN;
        const long long base = (long long)(t0 - 16) * CIN;
        const int nfl = CIN * NSTAGE;                        // 1911 floats
        for (int e4 = 4 * tid; e4 < nfl; e4 += 4 * 512) {
            long long src = base + e4;
            if (src >= 0 && src + 3 < (long long)S * CIN) {
                float4 v = *reinterpret_cast<const float4*>(xb + src);
                float va[4] = {v.x, v.y, v.z, v.w};
                #pragma unroll
                for (int u = 0; u < 4; ++u) {
                    int e = e4 + u;
                    int j = e / CIN, c = e - j * CIN;
                    xs[c * TROW + j] = va[u];
                }
            } else {
                #pragma unroll
                for (int u = 0; u < 4; ++u) {
                    int e = e4 + u;
                    if (e < nfl) {
                        int j = e / CIN, c = e - j * CIN;
                        int tm = t0 - 16 + j;
                        if (tm < 0) tm += S; else if (tm >= S) tm -= S;
                        xs[c * TROW + j] = xb[tm * CIN + c];
                    }
                }
            }
        }
    }

    // ---- per-thread weights in FIR tap order ----
    const int d  = tid;
    const int oo = d % KERN;
    const float* wrow = (d < DM - 1) ? (w_conv + oo * 18) : w_left;
    const float bias  = (d < DM - 1) ? b_conv[oo] : b_left[0];
    const int cc = (d < DM - 1) ? (d / KERN) : (CIN - 1);
    float g[18];
    #pragma unroll
    for (int off = 0; off < 18; ++off)
        g[off] = wrow[(5 - off / 3) * 3 + (off % 3)];
#if USE_DOT2
    half2_t g2[9];
    #pragma unroll
    for (int m = 0; m < 9; ++m)
        g2[m] = pkrtz(g[2*m], g[2*m+1]);
#endif

    __syncthreads();

    const float* xrow = xs + cc * TROW;
    float* const op = out + ((long long)b * S + t0) * DM + d;

    const bool edgetile = (tile == 0) || (tile == TILES - 1);

    for (int cc_ = 0; cc_ < NCH; ++cc_) {
        const int jb  = cc_ * CHUNK;
        const int tc  = t0 + jb;
        float* opc = op + jb * DM;

        if (!edgetile || !((tc < 16) || (tc + CHUNK >= S))) {
#if USE_DOT2
            do_chunk32_dot2(xrow + jb, g2, bias, opc);
#else
            do_chunk32_fma(xrow + jb, g, bias, opc);
#endif
        } else {
            // masked exact fp32 path (tile 0 chunk 0, tile 15 chunk 7 only)
            #pragma unroll
            for (int i = 0; i < CHUNK; ++i) {
                float p0 = 0.f, p1 = 0.f, p2 = 0.f;
                #pragma unroll
                for (int o = 0; o < 18; o += 3) {
                    p0 = fmaf(g[o],     xrow[jb + i + o],     p0);
                    p1 = fmaf(g[o + 1], xrow[jb + i + o + 1], p1);
                    p2 = fmaf(g[o + 2], xrow[jb + i + o + 2], p2);
                }
                const int t = tc + i;
                const float f0 = (t == 0 || t >= 16)     ? 1.f : 0.f;
                const float f1 = (t >= 15)               ? 1.f : 0.f;
                const float f2 = (t >= 14 && t != S - 1) ? 1.f : 0.f;
                opc[i * DM] = bias + f0 * p0 + f1 * p1 + f2 * p2;
            }
        }
    }
}

extern "C" void kernel_launch(void* const* d_in, const int* in_sizes, int n_in,
                              void* d_out, int out_size, void* d_ws, size_t ws_size,
                              hipStream_t stream) {
    const float* x      = (const float*)d_in[0];
    const float* w_conv = (const float*)d_in[1];
    const float* b_conv = (const float*)d_in[2];
    const float* w_left = (const float*)d_in[3];
    const float* b_left = (const float*)d_in[4];
    float* out = (float*)d_out;

    const int B = in_sizes[0] / (S * CIN);   // 32
    dim3 grid(B * TILES);
    tokemb_kernel<<<grid, 512, 0, stream>>>(x, w_conv, b_conv, w_left, b_left, out);
}